// Round 14
// baseline (519.297 us; speedup 1.0000x reference)
//
#include <hip/hip_runtime.h>

#define BB 4
#define SS 2048
#define DD 1024
#define HH 16
#define PFF 4096
#define MR 8192

typedef unsigned short u16;
typedef __attribute__((ext_vector_type(8))) short s16x8;   // MFMA A/B frag (8 bf16)
typedef __attribute__((ext_vector_type(4))) float f32x4v;  // 16x16 C/D frag
typedef __attribute__((ext_vector_type(16))) float f32x16; // 32x32 C/D frag
typedef __attribute__((ext_vector_type(4))) unsigned short u16x4;
typedef __attribute__((ext_vector_type(8))) unsigned short u16x8;

__device__ inline u16 f2bf(float f) {
  union { float f; unsigned u; } v; v.f = f;
  unsigned r = v.u + 0x7FFFu + ((v.u >> 16) & 1u);
  return (u16)(r >> 16);
}

__device__ inline float bf2f(u16 x) {
  union { unsigned u; float f; } v;
  v.u = ((unsigned)x) << 16;
  return v.f;
}

__device__ inline unsigned cvtpk_bf16(float lo, float hi) {
  unsigned r;
  asm("v_cvt_pk_bf16_f32 %0, %1, %2" : "=v"(r) : "v"(lo), "v"(hi));
  return r;
}

__device__ inline void gload16(const void* g, void* l) {
  __builtin_amdgcn_global_load_lds(
      (const __attribute__((address_space(1))) void*)g,
      (__attribute__((address_space(3))) void*)l, 16, 0, 0);
}

__device__ inline f32x4v MFMA(s16x8 a, s16x8 b, f32x4v c) {
  return __builtin_amdgcn_mfma_f32_16x16x32_bf16(a, b, c, 0, 0, 0);
}
__device__ inline f32x16 MFMA32(s16x8 a, s16x8 b, f32x16 c) {
  return __builtin_amdgcn_mfma_f32_32x32x16_bf16(a, b, c, 0, 0, 0);
}

#define RAWBAR()                          \
  do {                                    \
    asm volatile("" ::: "memory");        \
    __builtin_amdgcn_s_barrier();         \
    asm volatile("" ::: "memory");        \
  } while (0)
#define WAITVM(N) asm volatile("s_waitcnt vmcnt(" #N ")" ::: "memory")

// read a b128 fragment from a 64-col bf16 LDS tile with (row&7)<<4 byte-XOR swizzle
__device__ inline s16x8 ldfrag(const u16* base, int row, int colByte) {
  return *(const s16x8*)((const char*)base + row * 128 + (colByte ^ ((row & 7) << 4)));
}

// ---------------------------------------------------------------------------
// 256x256 deep-pipelined bf16 GEMM (T3+T4+T5): C = A[M,K] @ Bt[N,K]^T + bias.
// 512 thr (8 waves 2Mx4N), per-wave 128x64, vmcnt(4), 3-buffer ring, lead-2.
// SCQ: scale cols<DD by 0.125*log2e. VT: cols>=2048 -> Vt[bh*64+d][s].
// ---------------------------------------------------------------------------
template <int RELU, int OUTBF, int SCQ, int VT>
__global__ __launch_bounds__(512, 1) void gemm256(
    const u16* __restrict__ A, const u16* __restrict__ Bt,
    const float* __restrict__ bias, float* __restrict__ Cf,
    u16* __restrict__ Cb, u16* __restrict__ Vt, int M, int N, int K,
    int ntx) {
  constexpr int BUF = 16384;  // u16 per ring buffer (A 8K + B 8K)
  __shared__ __align__(128) u16 lds[3 * BUF];
  const int t = threadIdx.x;
  const int lane = t & 63, w = t >> 6;
  const int wr = w >> 2, wc = w & 3;
  const int g = lane >> 4, q = lane & 15;

  const int cpx = gridDim.x >> 3;
  const int wg = (blockIdx.x & 7) * cpx + (blockIdx.x >> 3);
  const int row0 = (wg / ntx) * 256, col0 = (wg % ntx) * 256;

  f32x4v acc[8][4];
#pragma unroll
  for (int m = 0; m < 8; ++m)
#pragma unroll
    for (int n = 0; n < 4; ++n) acc[m][n] = (f32x4v){0.f, 0.f, 0.f, 0.f};

  const int sr0 = t >> 2, sc0 = (t & 3) * 8;
  const u16* Ag0 = A + (size_t)(row0 + sr0) * K + sc0;
  const u16* Ag1 = A + (size_t)(row0 + sr0 + 128) * K + sc0;
  const u16* Bg0 = Bt + (size_t)(col0 + sr0) * K + sc0;
  const u16* Bg1 = Bt + (size_t)(col0 + sr0 + 128) * K + sc0;
  const int wud = (t & ~63) * 8;

#define STAGE_A(kt, buf)                                          \
  do {                                                            \
    u16* ab_ = &lds[(buf) * BUF];                                 \
    gload16(Ag0 + (kt) * 32, ab_ + wud);                          \
    gload16(Ag1 + (kt) * 32, ab_ + 4096 + wud);                   \
  } while (0)
#define STAGE_B(kt, buf)                                          \
  do {                                                            \
    u16* bb_ = &lds[(buf) * BUF + 8192];                          \
    gload16(Bg0 + (kt) * 32, bb_ + wud);                          \
    gload16(Bg1 + (kt) * 32, bb_ + 4096 + wud);                   \
  } while (0)

  const int NT = K / 32;
  STAGE_A(0, 0); STAGE_B(0, 0);
  STAGE_A(1, 1); STAGE_B(1, 1);
  WAITVM(4);
  RAWBAR();

  int cur = 0, nxt = 2;
  for (int kt = 0; kt < NT; ++kt) {
    const u16* ab = &lds[cur * BUF];
    const u16* bb = ab + 8192;
    const bool pf = (kt + 2 < NT);
    if (pf) STAGE_A(kt + 2, nxt);
    s16x8 bf_[4], af_[4];
#pragma unroll
    for (int n = 0; n < 4; ++n)
      bf_[n] = *(const s16x8*)&bb[(wc * 64 + n * 16 + q) * 32 + g * 8];
#pragma unroll
    for (int m = 0; m < 4; ++m)
      af_[m] = *(const s16x8*)&ab[(wr * 128 + m * 16 + q) * 32 + g * 8];
    RAWBAR();
    __builtin_amdgcn_s_setprio(1);
#pragma unroll
    for (int m = 0; m < 4; ++m)
#pragma unroll
      for (int n = 0; n < 4; ++n) acc[m][n] = MFMA(af_[m], bf_[n], acc[m][n]);
    __builtin_amdgcn_s_setprio(0);
    RAWBAR();
    if (pf) STAGE_B(kt + 2, nxt);
#pragma unroll
    for (int m = 0; m < 4; ++m)
      af_[m] = *(const s16x8*)&ab[(wr * 128 + (m + 4) * 16 + q) * 32 + g * 8];
    RAWBAR();
    __builtin_amdgcn_s_setprio(1);
#pragma unroll
    for (int m = 0; m < 4; ++m)
#pragma unroll
      for (int n = 0; n < 4; ++n)
        acc[m + 4][n] = MFMA(af_[m], bf_[n], acc[m + 4][n]);
    __builtin_amdgcn_s_setprio(0);
    if (kt + 1 < NT) {
      if (pf) WAITVM(4);
      else WAITVM(0);
    }
    RAWBAR();
    cur = (cur == 2) ? 0 : cur + 1;
    nxt = (nxt == 2) ? 0 : nxt + 1;
  }
#undef STAGE_A
#undef STAGE_B

#pragma unroll
  for (int n = 0; n < 4; ++n) {
    const int col = col0 + wc * 64 + 16 * n + q;
    const float bv = bias ? bias[col] : 0.f;
#pragma unroll
    for (int m = 0; m < 8; ++m) {
      const int row = row0 + wr * 128 + 16 * m + 4 * g;
      if (VT && col >= 2048) {
        const int hd = col - 2048;
        u16x4 o;
#pragma unroll
        for (int r = 0; r < 4; ++r) o[r] = f2bf(acc[m][n][r] + bv);
        *(u16x4*)&Vt[((size_t)((row >> 11) * 16 + (hd >> 6)) * 64 +
                      (hd & 63)) * SS + (row & 2047)] = o;
      } else {
#pragma unroll
        for (int r = 0; r < 4; ++r) {
          float v = acc[m][n][r] + bv;
          if (RELU) v = fmaxf(v, 0.f);
          if (SCQ && col < DD) v *= 0.18033688011112042f;  // 0.125*log2(e)
          if (OUTBF) Cb[(size_t)(row + r) * N + col] = f2bf(v);
          else Cf[(size_t)(row + r) * N + col] = v;
        }
      }
    }
  }
}

// ---------------------------------------------------------------------------
// 128x128 pipelined bf16 GEMM for N=1024 outputs (Wo, FFN2): 256 thr
// (4 waves 2Mx2N), 3-buffer 48KB ring, lead-2, vmcnt(4). Grid 512.
// ---------------------------------------------------------------------------
template <int RELU>
__global__ __launch_bounds__(256, 3) void gemm128(
    const u16* __restrict__ A, const u16* __restrict__ Bt,
    const float* __restrict__ bias, float* __restrict__ Cf,
    int M, int N, int K, int ntx) {
  constexpr int BUF = 8192;  // u16 per ring buffer (A 4K + B 4K)
  __shared__ __align__(128) u16 lds[3 * BUF];
  const int t = threadIdx.x;
  const int lane = t & 63, w = t >> 6;
  const int wr = w >> 1, wc = w & 1;
  const int g = lane >> 4, q = lane & 15;

  const int cpx = gridDim.x >> 3;
  const int wg = (blockIdx.x & 7) * cpx + (blockIdx.x >> 3);
  const int row0 = (wg / ntx) * 128, col0 = (wg % ntx) * 128;

  f32x4v acc[4][4];
#pragma unroll
  for (int m = 0; m < 4; ++m)
#pragma unroll
    for (int n = 0; n < 4; ++n) acc[m][n] = (f32x4v){0.f, 0.f, 0.f, 0.f};

  const int sr0 = t >> 2, sc0 = (t & 3) * 8;   // rows 0..63
  const u16* Ag0 = A + (size_t)(row0 + sr0) * K + sc0;
  const u16* Ag1 = A + (size_t)(row0 + sr0 + 64) * K + sc0;
  const u16* Bg0 = Bt + (size_t)(col0 + sr0) * K + sc0;
  const u16* Bg1 = Bt + (size_t)(col0 + sr0 + 64) * K + sc0;
  const int wud = (t & ~63) * 8;

#define STAGE_A(kt, buf)                                          \
  do {                                                            \
    u16* ab_ = &lds[(buf) * BUF];                                 \
    gload16(Ag0 + (kt) * 32, ab_ + wud);                          \
    gload16(Ag1 + (kt) * 32, ab_ + 2048 + wud);                   \
  } while (0)
#define STAGE_B(kt, buf)                                          \
  do {                                                            \
    u16* bb_ = &lds[(buf) * BUF + 4096];                          \
    gload16(Bg0 + (kt) * 32, bb_ + wud);                          \
    gload16(Bg1 + (kt) * 32, bb_ + 2048 + wud);                   \
  } while (0)

  const int NT = K / 32;
  STAGE_A(0, 0); STAGE_B(0, 0);
  STAGE_A(1, 1); STAGE_B(1, 1);
  WAITVM(4);
  RAWBAR();

  int cur = 0, nxt = 2;
  for (int kt = 0; kt < NT; ++kt) {
    const u16* ab = &lds[cur * BUF];
    const u16* bb = ab + 4096;
    const bool pf = (kt + 2 < NT);
    if (pf) STAGE_A(kt + 2, nxt);
    s16x8 bf_[4], af_[2];
#pragma unroll
    for (int n = 0; n < 4; ++n)
      bf_[n] = *(const s16x8*)&bb[(wc * 64 + n * 16 + q) * 32 + g * 8];
#pragma unroll
    for (int m = 0; m < 2; ++m)
      af_[m] = *(const s16x8*)&ab[(wr * 64 + m * 16 + q) * 32 + g * 8];
    RAWBAR();
    __builtin_amdgcn_s_setprio(1);
#pragma unroll
    for (int m = 0; m < 2; ++m)
#pragma unroll
      for (int n = 0; n < 4; ++n) acc[m][n] = MFMA(af_[m], bf_[n], acc[m][n]);
    __builtin_amdgcn_s_setprio(0);
    RAWBAR();
    if (pf) STAGE_B(kt + 2, nxt);
#pragma unroll
    for (int m = 0; m < 2; ++m)
      af_[m] = *(const s16x8*)&ab[(wr * 64 + (m + 2) * 16 + q) * 32 + g * 8];
    RAWBAR();
    __builtin_amdgcn_s_setprio(1);
#pragma unroll
    for (int m = 0; m < 2; ++m)
#pragma unroll
      for (int n = 0; n < 4; ++n)
        acc[m + 2][n] = MFMA(af_[m], bf_[n], acc[m + 2][n]);
    __builtin_amdgcn_s_setprio(0);
    if (kt + 1 < NT) {
      if (pf) WAITVM(4);
      else WAITVM(0);
    }
    RAWBAR();
    cur = (cur == 2) ? 0 : cur + 1;
    nxt = (nxt == 2) ? 0 : nxt + 1;
  }
#undef STAGE_A
#undef STAGE_B

#pragma unroll
  for (int n = 0; n < 4; ++n) {
    const int col = col0 + wc * 64 + 16 * n + q;
    const float bv = bias ? bias[col] : 0.f;
#pragma unroll
    for (int m = 0; m < 4; ++m) {
      const int row = row0 + wr * 64 + 16 * m + 4 * g;
#pragma unroll
      for (int r = 0; r < 4; ++r) {
        float v = acc[m][n][r] + bv;
        if (RELU) v = fmaxf(v, 0.f);
        Cf[(size_t)(row + r) * N + col] = v;
      }
    }
  }
}

// ---------------------------------------------------------------------------
// Flash attention v8 (R12): k-split waves, unroll-2 static bases.
// launch_bounds(256,5): 5 blocks/CU (LDS 5x32KB = 160KB exactly).
// ---------------------------------------------------------------------------
__global__ __launch_bounds__(256, 5) void attn_mfma(
    const u16* __restrict__ qkv, const u16* __restrict__ vt,
    u16* __restrict__ xb) {
  __shared__ __align__(128) u16 lds[16384];  // 2 x 16KB bufs

  const int t = threadIdx.x;
  const int w = t >> 6, lane = t & 63;
  const int q = lane & 31, hi = lane >> 5;
  const int qg = w >> 1;   // q-group (0,1)
  const int kg = w & 1;    // k-group (0,1)

  const int flat = blockIdx.x;          // 0..2047
  const int xcd = flat & 7;
  const int j = flat >> 3;              // 0..255
  const int bh = xcd * 8 + (j & 7);
  const int qb = j >> 3;                // 0..31
  const int b = bh >> 4, h = bh & 15;
  const int q0 = qb * 64;
  const int qcol = h * 64, kcol = DD + h * 64;

  const int r0 = t >> 3;                       // 0..31
  const int sc = ((t & 7) ^ (r0 & 7)) * 8;
  const int ldst = (t & ~63) * 16;             // wave-uniform byte base

  const u16* ks0 = qkv + (size_t)(b * SS + r0) * 3072 + kcol + sc;
  const u16* ks1 = ks0 + (size_t)32 * 3072;
  const u16* vs0 = vt + (size_t)(bh * 64 + r0) * SS + sc;
  const u16* vs1 = vs0 + (size_t)32 * SS;

  {
    const u16* Qsrc = qkv + (size_t)(b * SS + q0 + r0) * 3072 + qcol + sc;
    gload16(Qsrc, (char*)lds + ldst);
    gload16(Qsrc + (size_t)32 * 3072, (char*)lds + 4096 + ldst);
  }
  WAITVM(0);
  RAWBAR();
  s16x8 qf[4];
  {
    const u16* Qw = lds + qg * 2048;
#pragma unroll
    for (int s = 0; s < 4; ++s) qf[s] = ldfrag(Qw, q, 32 * s + 16 * hi);
  }
  asm volatile("s_waitcnt lgkmcnt(0)" ::: "memory");
  __builtin_amdgcn_sched_barrier(0);
  RAWBAR();

#define STAGE(B)                                              \
  do {                                                        \
    gload16(ks0, (char*)lds + (B) + ldst);                    \
    gload16(ks1, (char*)lds + (B) + 4096 + ldst);             \
    gload16(vs0, (char*)lds + (B) + 8192 + ldst);             \
    gload16(vs1, (char*)lds + (B) + 12288 + ldst);            \
    ks0 += (size_t)64 * 3072; ks1 += (size_t)64 * 3072;       \
    vs0 += 64; vs1 += 64;                                     \
  } while (0)

  s16x8 onesv;
#pragma unroll
  for (int i = 0; i < 8; ++i) onesv[i] = (short)0x3F80;  // bf16 1.0

  f32x16 zf;
#pragma unroll
  for (int i = 0; i < 16; ++i) zf[i] = 0.f;

  f32x16 oac0, oac1, lacc;
#pragma unroll
  for (int i = 0; i < 16; ++i) { oac0[i] = 0.f; oac1[i] = 0.f; lacc[i] = 0.f; }

  auto compute = [&](const int B) {
    const u16* Kc = lds + B / 2;
    const u16* Vc = Kc + 4096;

    __builtin_amdgcn_s_setprio(1);
    s16x8 k0 = ldfrag(Kc, kg * 32 + q, 16 * hi);
    f32x16 sa = MFMA32(k0, qf[0], zf);
#pragma unroll
    for (int s = 1; s < 4; ++s) {
      s16x8 ks = ldfrag(Kc, kg * 32 + q, 32 * s + 16 * hi);
      sa = MFMA32(ks, qf[s], sa);
    }
    __builtin_amdgcn_s_setprio(0);

#pragma unroll
    for (int i = 0; i < 16; ++i) sa[i] = exp2f(sa[i]);

    __builtin_amdgcn_s_setprio(1);
#pragma unroll
    for (int sp = 0; sp < 2; ++sp) {
      const int rb = 8 * sp;
      unsigned x0 = cvtpk_bf16(sa[rb + 0], sa[rb + 1]);
      unsigned x1 = cvtpk_bf16(sa[rb + 2], sa[rb + 3]);
      unsigned y0 = cvtpk_bf16(sa[rb + 4], sa[rb + 5]);
      unsigned y1 = cvtpk_bf16(sa[rb + 6], sa[rb + 7]);
      asm("v_permlane32_swap_b32 %0, %1" : "+v"(x0), "+v"(y0));
      asm("v_permlane32_swap_b32 %0, %1" : "+v"(x1), "+v"(y1));
      union { unsigned u[4]; s16x8 v; } pfv;
      pfv.u[0] = x0; pfv.u[1] = x1; pfv.u[2] = y0; pfv.u[3] = y1;
      s16x8 v0 = ldfrag(Vc, q, kg * 64 + 32 * sp + 16 * hi);
      s16x8 v1 = ldfrag(Vc, 32 + q, kg * 64 + 32 * sp + 16 * hi);
      oac0 = MFMA32(v0, pfv.v, oac0);
      oac1 = MFMA32(v1, pfv.v, oac1);
      lacc = MFMA32(onesv, pfv.v, lacc);
    }
    __builtin_amdgcn_s_setprio(0);
  };

  STAGE(0);
  WAITVM(0);
  RAWBAR();
  for (int i = 0; i < 15; ++i) {
    STAGE(16384);
    compute(0);
    WAITVM(0);
    RAWBAR();
    STAGE(0);
    compute(16384);
    WAITVM(0);
    RAWBAR();
  }
  STAGE(16384);
  compute(0);
  WAITVM(0);
  RAWBAR();
  compute(16384);
#undef STAGE

  __syncthreads();
  float* red = (float*)lds;
  if (kg == 1) {
    float* myr = red + (qg * 64 + lane) * 33;
#pragma unroll
    for (int i = 0; i < 16; ++i) { myr[i] = oac0[i]; myr[16 + i] = oac1[i]; }
    myr[32] = lacc[0];
  }
  __syncthreads();
  if (kg == 0) {
    const float* pr = red + (qg * 64 + lane) * 33;
#pragma unroll
    for (int i = 0; i < 16; ++i) { oac0[i] += pr[i]; oac1[i] += pr[16 + i]; }
    const float inv = 1.f / (lacc[0] + pr[32]);
    const size_t row = (size_t)(b * SS + q0 + qg * 32 + q);
    u16* orow = xb + row * DD + qcol;
#pragma unroll
    for (int rr = 0; rr < 4; ++rr) {
      uint2 pw0, pw1;
      pw0.x = cvtpk_bf16(oac0[4 * rr] * inv, oac0[4 * rr + 1] * inv);
      pw0.y = cvtpk_bf16(oac0[4 * rr + 2] * inv, oac0[4 * rr + 3] * inv);
      pw1.x = cvtpk_bf16(oac1[4 * rr] * inv, oac1[4 * rr + 1] * inv);
      pw1.y = cvtpk_bf16(oac1[4 * rr + 2] * inv, oac1[4 * rr + 3] * inv);
      *(uint2*)(orow + 8 * rr + 4 * hi) = pw0;
      *(uint2*)(orow + 32 + 8 * rr + 4 * hi) = pw1;
    }
  }
}

// ---------------------------------------------------------------------------
// prep_all: one kernel for all preprocessing (replaces 8 launches).
// blocks [0,8192): src f32 -> bf16; [8192,12288): Wq/Wk/Wv/Wo transpose;
// [12288,16384): W1; [16384,20480): W2; [20480,20492): bias concat.
// (verified correct in R10)
// ---------------------------------------------------------------------------
__global__ __launch_bounds__(256) void prep_all(
    const float* __restrict__ src, u16* __restrict__ srcb,
    const float* __restrict__ Wq, const float* __restrict__ Wk,
    const float* __restrict__ Wv, const float* __restrict__ Wo,
    u16* __restrict__ wqkvT, u16* __restrict__ woT,
    const float* __restrict__ W1, u16* __restrict__ w1T,
    const float* __restrict__ W2, u16* __restrict__ w2T,
    const float* __restrict__ bq, const float* __restrict__ bk,
    const float* __restrict__ bvv, float* __restrict__ bqkv) {
  const int id = blockIdx.x;
  const int t = threadIdx.x;
  __shared__ float T[32][33];

  if (id < 8192) {  // cvt
    int i = id * 256 + t;
    float4 v = ((const float4*)src)[i];
    u16x4 o;
    o[0] = f2bf(v.x); o[1] = f2bf(v.y); o[2] = f2bf(v.z); o[3] = f2bf(v.w);
    ((u16x4*)srcb)[i] = o;
    return;
  }
  const int id2 = id - 8192;
  if (id2 >= 12288) {  // concat
    int i = (id2 - 12288) * 256 + t;
    if (i < 3072)
      bqkv[i] = i < 1024 ? bq[i] : (i < 2048 ? bk[i - 1024] : bvv[i - 2048]);
    return;
  }
  const float* W; u16* Wt; int K, N, bx, by;
  if (id2 < 4096) {
    const int which = id2 >> 10, tile = id2 & 1023;
    W = (which == 0) ? Wq : (which == 1) ? Wk : (which == 2) ? Wv : Wo;
    Wt = (which == 3) ? woT : wqkvT + (size_t)which * 1024 * 1024;
    K = 1024; N = 1024; bx = tile & 31; by = tile >> 5;
  } else if (id2 < 8192) {
    const int tile = id2 - 4096;
    W = W1; Wt = w1T; K = 1024; N = 4096; bx = tile & 127; by = tile >> 7;
  } else {
    const int tile = id2 - 8192;
    W = W2; Wt = w2T; K = 4096; N = 1024; bx = tile & 31; by = tile >> 5;
  }
  const int n0 = bx * 32, k0 = by * 32;
  const int r = t >> 3, c = (t & 7) * 4;
  float4 v = *(const float4*)&W[(size_t)(k0 + r) * N + n0 + c];
  T[r][c] = v.x; T[r][c + 1] = v.y; T[r][c + 2] = v.z; T[r][c + 3] = v.w;
  __syncthreads();
  const int a = t >> 3, b0 = (t & 7) * 4;
  u16x4 o;
#pragma unroll
  for (int jj = 0; jj < 4; ++jj) o[jj] = f2bf(T[b0 + jj][a]);
  *(u16x4*)&Wt[(size_t)(n0 + a) * K + k0 + b0] = o;
}

// ---------------------------------------------------------------------------
// Residual + LayerNorm. XBF: X supplied as bf16. WB: write bf16. WF: write f32.
// ---------------------------------------------------------------------------
template <int WB, int WF, int XBF>
__global__ __launch_bounds__(256) void ln_res(
    const float* __restrict__ Xf, const u16* __restrict__ Xb,
    const float* __restrict__ R, const float* __restrict__ g,
    const float* __restrict__ b, float* __restrict__ Y,
    u16* __restrict__ Yb) {
  const int row = blockIdx.x;
  const int t = threadIdx.x;
  const size_t off = (size_t)row * DD + t * 4;

  float v0, v1, v2, v3;
  if (XBF) {
    u16x4 x4 = *(const u16x4*)&Xb[off];
    v0 = bf2f(x4[0]); v1 = bf2f(x4[1]); v2 = bf2f(x4[2]); v3 = bf2f(x4[3]);
  } else {
    float4 x4 = *(const float4*)&Xf[off];
    v0 = x4.x; v1 = x4.y; v2 = x4.z; v3 = x4.w;
  }
  float4 r4 = *(const float4*)&R[off];
  v0 += r4.x; v1 += r4.y; v2 += r4.z; v3 += r4.w;

  float s1 = v0 + v1 + v2 + v3;
  float s2 = v0 * v0 + v1 * v1 + v2 * v2 + v3 * v3;
#pragma unroll
  for (int o = 1; o < 64; o <<= 1) {
    s1 += __shfl_xor(s1, o);
    s2 += __shfl_xor(s2, o);
  }
  __shared__ float red1[4], red2[4];
  if ((t & 63) == 0) {
    red1[t >> 6] = s1;
    red2[t >> 6] = s2;
  }
  __syncthreads();
  s1 = red1[0] + red1[1] + red1[2] + red1[3];
  s2 = red2[0] + red2[1] + red2[2] + red2[3];

  const float mu = s1 * (1.f / DD);
  const float var = s2 * (1.f / DD) - mu * mu;
  const float rs = rsqrtf(var + 1e-5f);

  float4 g4 = *(const float4*)&g[t * 4];
  float4 b4 = *(const float4*)&b[t * 4];
  float4 y;
  y.x = (v0 - mu) * rs * g4.x + b4.x;
  y.y = (v1 - mu) * rs * g4.y + b4.y;
  y.z = (v2 - mu) * rs * g4.z + b4.z;
  y.w = (v3 - mu) * rs * g4.w + b4.w;
  if (WF) *(float4*)&Y[off] = y;
  if (WB) {
    u16x4 o;
    o[0] = f2bf(y.x); o[1] = f2bf(y.y); o[2] = f2bf(y.z); o[3] = f2bf(y.w);
    *(u16x4*)&Yb[off] = o;
  }
}

// ---------------------------------------------------------------------------
extern "C" void kernel_launch(void* const* d_in, const int* in_sizes, int n_in,
                              void* d_out, int out_size, void* d_ws,
                              size_t ws_size, hipStream_t stream) {
  const float* src = (const float*)d_in[0];
  const float* Wq  = (const float*)d_in[1];
  const float* bq  = (const float*)d_in[2];
  const float* Wk  = (const float*)d_in[3];
  const float* bk  = (const float*)d_in[4];
  const float* Wv  = (const float*)d_in[5];
  const float* bv  = (const float*)d_in[6];
  const float* Wo  = (const float*)d_in[7];
  const float* bo  = (const float*)d_in[8];
  const float* g1  = (const float*)d_in[9];
  const float* b1  = (const float*)d_in[10];
  const float* W1  = (const float*)d_in[11];
  const float* bf1 = (const float*)d_in[12];
  const float* W2  = (const float*)d_in[13];
  const float* bf2 = (const float*)d_in[14];
  const float* g2  = (const float*)d_in[15];
  const float* b2  = (const float*)d_in[16];

  char* W = (char*)d_ws;
  u16*   wqkvT = (u16*)  (W + 0);          //  6,291,456
  u16*   woT   = (u16*)  (W + 6291456);    //  2,097,152
  u16*   w1T   = (u16*)  (W + 8388608);    //  8,388,608
  u16*   w2T   = (u16*)  (W + 16777216);   //  8,388,608
  float* bqkv  = (float*)(W + 25165824);   //     12,288
  u16*   srcb  = (u16*)  (W + 25178112);   // 16,777,216
  u16*   qkv   = (u16*)  (W + 41955328);   // 50,331,648 (V cols unused)
  u16*   vt    = (u16*)  (W + 92286976);   // 16,777,216
  u16*   xb    = (u16*)  (W + 109064192);  // 16,777,216
  float* pb    = (float*)(W + 125841408);  // 33,554,432
  u16*   s1bb  = (u16*)  (W + 109064192);  // alias xb (dead after Wo GEMM)
  u16*   f1b   = (u16*)  (W + 41955328);   // alias qkv+vt (dead after attn)
  float* f2b   = (float*)(W + 125841408);  // alias pb (dead after LN1)

  dim3 blk(256);

  // all prep in one launch (cvt + 6 transposes + concat)
  prep_all<<<20492, blk, 0, stream>>>(src, srcb, Wq, Wk, Wv, Wo, wqkvT, woT,
                                      W1, w1T, W2, w2T, bq, bk, bv, bqkv);

  // fused QKV projection: Q (pre-scaled) + K -> qkv; V -> vt (transposed)
  gemm256<0, 1, 1, 1><<<384, 512, 0, stream>>>(
      srcb, wqkvT, bqkv, nullptr, qkv, vt, MR, 3072, DD, 12);
  // attention v8 (5 blocks/CU)
  attn_mfma<<<2048, blk, 0, stream>>>(qkv, vt, xb);
  // output projection (128x128)
  gemm128<0><<<512, blk, 0, stream>>>(xb, woT, bo, pb, MR, DD, DD, 8);
  // residual + LN1 -> bf16 only
  ln_res<1, 0, 0><<<MR, blk, 0, stream>>>(src, nullptr, pb, g1, b1, nullptr,
                                          s1bb);
  // FFN1 (ReLU, bf16 out)
  gemm256<1, 1, 0, 0><<<512, 512, 0, stream>>>(
      s1bb, w1T, bf1, nullptr, f1b, nullptr, MR, PFF, DD, 16);
  // FFN2 (f32 out, 128x128)
  gemm128<0><<<512, blk, 0, stream>>>(f1b, w2T, bf2, f2b, MR, DD, PFF, 8);
  // residual (bf16 s1) + LN2 -> output f32
  ln_res<0, 1, 1><<<MR, blk, 0, stream>>>(nullptr, s1bb, f2b, g2, b2,
                                          (float*)d_out, nullptr);
}

// Round 15
// 428.610 us; speedup vs baseline: 1.2116x; 1.2116x over previous
//
#include <hip/hip_runtime.h>

#define BB 4
#define SS 2048
#define DD 1024
#define HH 16
#define PFF 4096
#define MR 8192

typedef unsigned short u16;
typedef __attribute__((ext_vector_type(8))) short s16x8;   // MFMA A/B frag (8 bf16)
typedef __attribute__((ext_vector_type(4))) float f32x4v;  // 16x16 C/D frag
typedef __attribute__((ext_vector_type(16))) float f32x16; // 32x32 C/D frag
typedef __attribute__((ext_vector_type(4))) unsigned short u16x4;
typedef __attribute__((ext_vector_type(8))) unsigned short u16x8;

__device__ inline u16 f2bf(float f) {
  union { float f; unsigned u; } v; v.f = f;
  unsigned r = v.u + 0x7FFFu + ((v.u >> 16) & 1u);
  return (u16)(r >> 16);
}

__device__ inline float bf2f(u16 x) {
  union { unsigned u; float f; } v;
  v.u = ((unsigned)x) << 16;
  return v.f;
}

__device__ inline unsigned cvtpk_bf16(float lo, float hi) {
  unsigned r;
  asm("v_cvt_pk_bf16_f32 %0, %1, %2" : "=v"(r) : "v"(lo), "v"(hi));
  return r;
}

__device__ inline void gload16(const void* g, void* l) {
  __builtin_amdgcn_global_load_lds(
      (const __attribute__((address_space(1))) void*)g,
      (__attribute__((address_space(3))) void*)l, 16, 0, 0);
}

__device__ inline f32x4v MFMA(s16x8 a, s16x8 b, f32x4v c) {
  return __builtin_amdgcn_mfma_f32_16x16x32_bf16(a, b, c, 0, 0, 0);
}
__device__ inline f32x16 MFMA32(s16x8 a, s16x8 b, f32x16 c) {
  return __builtin_amdgcn_mfma_f32_32x32x16_bf16(a, b, c, 0, 0, 0);
}

#define RAWBAR()                          \
  do {                                    \
    asm volatile("" ::: "memory");        \
    __builtin_amdgcn_s_barrier();         \
    asm volatile("" ::: "memory");        \
  } while (0)
#define WAITVM(N) asm volatile("s_waitcnt vmcnt(" #N ")" ::: "memory")

// read a b128 fragment from a 64-col bf16 LDS tile with (row&7)<<4 byte-XOR swizzle
__device__ inline s16x8 ldfrag(const u16* base, int row, int colByte) {
  return *(const s16x8*)((const char*)base + row * 128 + (colByte ^ ((row & 7) << 4)));
}

// ---------------------------------------------------------------------------
// 256x256 deep-pipelined bf16 GEMM (T3+T4+T5): C = A[M,K] @ Bt[N,K]^T + bias.
// 512 thr (8 waves 2Mx4N), per-wave 128x64, vmcnt(4), 3-buffer ring, lead-2.
// SCQ: scale cols<DD by 0.125*log2e. VT: cols>=2048 -> Vt[bh*64+d][s].
// ---------------------------------------------------------------------------
template <int RELU, int OUTBF, int SCQ, int VT>
__global__ __launch_bounds__(512, 1) void gemm256(
    const u16* __restrict__ A, const u16* __restrict__ Bt,
    const float* __restrict__ bias, float* __restrict__ Cf,
    u16* __restrict__ Cb, u16* __restrict__ Vt, int M, int N, int K,
    int ntx) {
  constexpr int BUF = 16384;  // u16 per ring buffer (A 8K + B 8K)
  __shared__ __align__(128) u16 lds[3 * BUF];
  const int t = threadIdx.x;
  const int lane = t & 63, w = t >> 6;
  const int wr = w >> 2, wc = w & 3;
  const int g = lane >> 4, q = lane & 15;

  const int cpx = gridDim.x >> 3;
  const int wg = (blockIdx.x & 7) * cpx + (blockIdx.x >> 3);
  const int row0 = (wg / ntx) * 256, col0 = (wg % ntx) * 256;

  f32x4v acc[8][4];
#pragma unroll
  for (int m = 0; m < 8; ++m)
#pragma unroll
    for (int n = 0; n < 4; ++n) acc[m][n] = (f32x4v){0.f, 0.f, 0.f, 0.f};

  const int sr0 = t >> 2, sc0 = (t & 3) * 8;
  const u16* Ag0 = A + (size_t)(row0 + sr0) * K + sc0;
  const u16* Ag1 = A + (size_t)(row0 + sr0 + 128) * K + sc0;
  const u16* Bg0 = Bt + (size_t)(col0 + sr0) * K + sc0;
  const u16* Bg1 = Bt + (size_t)(col0 + sr0 + 128) * K + sc0;
  const int wud = (t & ~63) * 8;

#define STAGE_A(kt, buf)                                          \
  do {                                                            \
    u16* ab_ = &lds[(buf) * BUF];                                 \
    gload16(Ag0 + (kt) * 32, ab_ + wud);                          \
    gload16(Ag1 + (kt) * 32, ab_ + 4096 + wud);                   \
  } while (0)
#define STAGE_B(kt, buf)                                          \
  do {                                                            \
    u16* bb_ = &lds[(buf) * BUF + 8192];                          \
    gload16(Bg0 + (kt) * 32, bb_ + wud);                          \
    gload16(Bg1 + (kt) * 32, bb_ + 4096 + wud);                   \
  } while (0)

  const int NT = K / 32;
  STAGE_A(0, 0); STAGE_B(0, 0);
  STAGE_A(1, 1); STAGE_B(1, 1);
  WAITVM(4);
  RAWBAR();

  int cur = 0, nxt = 2;
  for (int kt = 0; kt < NT; ++kt) {
    const u16* ab = &lds[cur * BUF];
    const u16* bb = ab + 8192;
    const bool pf = (kt + 2 < NT);
    if (pf) STAGE_A(kt + 2, nxt);
    s16x8 bf_[4], af_[4];
#pragma unroll
    for (int n = 0; n < 4; ++n)
      bf_[n] = *(const s16x8*)&bb[(wc * 64 + n * 16 + q) * 32 + g * 8];
#pragma unroll
    for (int m = 0; m < 4; ++m)
      af_[m] = *(const s16x8*)&ab[(wr * 128 + m * 16 + q) * 32 + g * 8];
    RAWBAR();
    __builtin_amdgcn_s_setprio(1);
#pragma unroll
    for (int m = 0; m < 4; ++m)
#pragma unroll
      for (int n = 0; n < 4; ++n) acc[m][n] = MFMA(af_[m], bf_[n], acc[m][n]);
    __builtin_amdgcn_s_setprio(0);
    RAWBAR();
    if (pf) STAGE_B(kt + 2, nxt);
#pragma unroll
    for (int m = 0; m < 4; ++m)
      af_[m] = *(const s16x8*)&ab[(wr * 128 + (m + 4) * 16 + q) * 32 + g * 8];
    RAWBAR();
    __builtin_amdgcn_s_setprio(1);
#pragma unroll
    for (int m = 0; m < 4; ++m)
#pragma unroll
      for (int n = 0; n < 4; ++n)
        acc[m + 4][n] = MFMA(af_[m], bf_[n], acc[m + 4][n]);
    __builtin_amdgcn_s_setprio(0);
    if (kt + 1 < NT) {
      if (pf) WAITVM(4);
      else WAITVM(0);
    }
    RAWBAR();
    cur = (cur == 2) ? 0 : cur + 1;
    nxt = (nxt == 2) ? 0 : nxt + 1;
  }
#undef STAGE_A
#undef STAGE_B

#pragma unroll
  for (int n = 0; n < 4; ++n) {
    const int col = col0 + wc * 64 + 16 * n + q;
    const float bv = bias ? bias[col] : 0.f;
#pragma unroll
    for (int m = 0; m < 8; ++m) {
      const int row = row0 + wr * 128 + 16 * m + 4 * g;
      if (VT && col >= 2048) {
        const int hd = col - 2048;
        u16x4 o;
#pragma unroll
        for (int r = 0; r < 4; ++r) o[r] = f2bf(acc[m][n][r] + bv);
        *(u16x4*)&Vt[((size_t)((row >> 11) * 16 + (hd >> 6)) * 64 +
                      (hd & 63)) * SS + (row & 2047)] = o;
      } else {
#pragma unroll
        for (int r = 0; r < 4; ++r) {
          float v = acc[m][n][r] + bv;
          if (RELU) v = fmaxf(v, 0.f);
          if (SCQ && col < DD) v *= 0.18033688011112042f;  // 0.125*log2(e)
          if (OUTBF) Cb[(size_t)(row + r) * N + col] = f2bf(v);
          else Cf[(size_t)(row + r) * N + col] = v;
        }
      }
    }
  }
}

// ---------------------------------------------------------------------------
// 128x128 pipelined bf16 GEMM for N=1024 outputs (Wo, FFN2): 256 thr
// (4 waves 2Mx2N), 3-buffer 48KB ring, lead-2, vmcnt(4). Grid 512.
// ---------------------------------------------------------------------------
template <int RELU>
__global__ __launch_bounds__(256, 3) void gemm128(
    const u16* __restrict__ A, const u16* __restrict__ Bt,
    const float* __restrict__ bias, float* __restrict__ Cf,
    int M, int N, int K, int ntx) {
  constexpr int BUF = 8192;  // u16 per ring buffer (A 4K + B 4K)
  __shared__ __align__(128) u16 lds[3 * BUF];
  const int t = threadIdx.x;
  const int lane = t & 63, w = t >> 6;
  const int wr = w >> 1, wc = w & 1;
  const int g = lane >> 4, q = lane & 15;

  const int cpx = gridDim.x >> 3;
  const int wg = (blockIdx.x & 7) * cpx + (blockIdx.x >> 3);
  const int row0 = (wg / ntx) * 128, col0 = (wg % ntx) * 128;

  f32x4v acc[4][4];
#pragma unroll
  for (int m = 0; m < 4; ++m)
#pragma unroll
    for (int n = 0; n < 4; ++n) acc[m][n] = (f32x4v){0.f, 0.f, 0.f, 0.f};

  const int sr0 = t >> 2, sc0 = (t & 3) * 8;   // rows 0..63
  const u16* Ag0 = A + (size_t)(row0 + sr0) * K + sc0;
  const u16* Ag1 = A + (size_t)(row0 + sr0 + 64) * K + sc0;
  const u16* Bg0 = Bt + (size_t)(col0 + sr0) * K + sc0;
  const u16* Bg1 = Bt + (size_t)(col0 + sr0 + 64) * K + sc0;
  const int wud = (t & ~63) * 8;

#define STAGE_A(kt, buf)                                          \
  do {                                                            \
    u16* ab_ = &lds[(buf) * BUF];                                 \
    gload16(Ag0 + (kt) * 32, ab_ + wud);                          \
    gload16(Ag1 + (kt) * 32, ab_ + 2048 + wud);                   \
  } while (0)
#define STAGE_B(kt, buf)                                          \
  do {                                                            \
    u16* bb_ = &lds[(buf) * BUF + 4096];                          \
    gload16(Bg0 + (kt) * 32, bb_ + wud);                          \
    gload16(Bg1 + (kt) * 32, bb_ + 2048 + wud);                   \
  } while (0)

  const int NT = K / 32;
  STAGE_A(0, 0); STAGE_B(0, 0);
  STAGE_A(1, 1); STAGE_B(1, 1);
  WAITVM(4);
  RAWBAR();

  int cur = 0, nxt = 2;
  for (int kt = 0; kt < NT; ++kt) {
    const u16* ab = &lds[cur * BUF];
    const u16* bb = ab + 4096;
    const bool pf = (kt + 2 < NT);
    if (pf) STAGE_A(kt + 2, nxt);
    s16x8 bf_[4], af_[2];
#pragma unroll
    for (int n = 0; n < 4; ++n)
      bf_[n] = *(const s16x8*)&bb[(wc * 64 + n * 16 + q) * 32 + g * 8];
#pragma unroll
    for (int m = 0; m < 2; ++m)
      af_[m] = *(const s16x8*)&ab[(wr * 64 + m * 16 + q) * 32 + g * 8];
    RAWBAR();
    __builtin_amdgcn_s_setprio(1);
#pragma unroll
    for (int m = 0; m < 2; ++m)
#pragma unroll
      for (int n = 0; n < 4; ++n) acc[m][n] = MFMA(af_[m], bf_[n], acc[m][n]);
    __builtin_amdgcn_s_setprio(0);
    RAWBAR();
    if (pf) STAGE_B(kt + 2, nxt);
#pragma unroll
    for (int m = 0; m < 2; ++m)
      af_[m] = *(const s16x8*)&ab[(wr * 64 + (m + 2) * 16 + q) * 32 + g * 8];
    RAWBAR();
    __builtin_amdgcn_s_setprio(1);
#pragma unroll
    for (int m = 0; m < 2; ++m)
#pragma unroll
      for (int n = 0; n < 4; ++n)
        acc[m + 2][n] = MFMA(af_[m], bf_[n], acc[m + 2][n]);
    __builtin_amdgcn_s_setprio(0);
    if (kt + 1 < NT) {
      if (pf) WAITVM(4);
      else WAITVM(0);
    }
    RAWBAR();
    cur = (cur == 2) ? 0 : cur + 1;
    nxt = (nxt == 2) ? 0 : nxt + 1;
  }
#undef STAGE_A
#undef STAGE_B

#pragma unroll
  for (int n = 0; n < 4; ++n) {
    const int col = col0 + wc * 64 + 16 * n + q;
    const float bv = bias ? bias[col] : 0.f;
#pragma unroll
    for (int m = 0; m < 4; ++m) {
      const int row = row0 + wr * 64 + 16 * m + 4 * g;
#pragma unroll
      for (int r = 0; r < 4; ++r) {
        float v = acc[m][n][r] + bv;
        if (RELU) v = fmaxf(v, 0.f);
        Cf[(size_t)(row + r) * N + col] = v;
      }
    }
  }
}

// ---------------------------------------------------------------------------
// Flash attention v8 (R12/R13-proven, 114us): k-split waves, unroll-2 static
// bases, launch_bounds(256,4) — (256,5) forces 48 VGPR and SPILLS (R14).
// ---------------------------------------------------------------------------
__global__ __launch_bounds__(256, 4) void attn_mfma(
    const u16* __restrict__ qkv, const u16* __restrict__ vt,
    u16* __restrict__ xb) {
  __shared__ __align__(128) u16 lds[16384];  // 2 x 16KB bufs

  const int t = threadIdx.x;
  const int w = t >> 6, lane = t & 63;
  const int q = lane & 31, hi = lane >> 5;
  const int qg = w >> 1;   // q-group (0,1)
  const int kg = w & 1;    // k-group (0,1)

  const int flat = blockIdx.x;          // 0..2047
  const int xcd = flat & 7;
  const int j = flat >> 3;              // 0..255
  const int bh = xcd * 8 + (j & 7);
  const int qb = j >> 3;                // 0..31
  const int b = bh >> 4, h = bh & 15;
  const int q0 = qb * 64;
  const int qcol = h * 64, kcol = DD + h * 64;

  const int r0 = t >> 3;                       // 0..31
  const int sc = ((t & 7) ^ (r0 & 7)) * 8;
  const int ldst = (t & ~63) * 16;             // wave-uniform byte base

  const u16* ks0 = qkv + (size_t)(b * SS + r0) * 3072 + kcol + sc;
  const u16* ks1 = ks0 + (size_t)32 * 3072;
  const u16* vs0 = vt + (size_t)(bh * 64 + r0) * SS + sc;
  const u16* vs1 = vs0 + (size_t)32 * SS;

  {
    const u16* Qsrc = qkv + (size_t)(b * SS + q0 + r0) * 3072 + qcol + sc;
    gload16(Qsrc, (char*)lds + ldst);
    gload16(Qsrc + (size_t)32 * 3072, (char*)lds + 4096 + ldst);
  }
  WAITVM(0);
  RAWBAR();
  s16x8 qf[4];
  {
    const u16* Qw = lds + qg * 2048;
#pragma unroll
    for (int s = 0; s < 4; ++s) qf[s] = ldfrag(Qw, q, 32 * s + 16 * hi);
  }
  asm volatile("s_waitcnt lgkmcnt(0)" ::: "memory");
  __builtin_amdgcn_sched_barrier(0);
  RAWBAR();

#define STAGE(B)                                              \
  do {                                                        \
    gload16(ks0, (char*)lds + (B) + ldst);                    \
    gload16(ks1, (char*)lds + (B) + 4096 + ldst);             \
    gload16(vs0, (char*)lds + (B) + 8192 + ldst);             \
    gload16(vs1, (char*)lds + (B) + 12288 + ldst);            \
    ks0 += (size_t)64 * 3072; ks1 += (size_t)64 * 3072;       \
    vs0 += 64; vs1 += 64;                                     \
  } while (0)

  s16x8 onesv;
#pragma unroll
  for (int i = 0; i < 8; ++i) onesv[i] = (short)0x3F80;  // bf16 1.0

  f32x16 zf;
#pragma unroll
  for (int i = 0; i < 16; ++i) zf[i] = 0.f;

  f32x16 oac0, oac1, lacc;
#pragma unroll
  for (int i = 0; i < 16; ++i) { oac0[i] = 0.f; oac1[i] = 0.f; lacc[i] = 0.f; }

  auto compute = [&](const int B) {
    const u16* Kc = lds + B / 2;
    const u16* Vc = Kc + 4096;

    __builtin_amdgcn_s_setprio(1);
    s16x8 k0 = ldfrag(Kc, kg * 32 + q, 16 * hi);
    f32x16 sa = MFMA32(k0, qf[0], zf);
#pragma unroll
    for (int s = 1; s < 4; ++s) {
      s16x8 ks = ldfrag(Kc, kg * 32 + q, 32 * s + 16 * hi);
      sa = MFMA32(ks, qf[s], sa);
    }
    __builtin_amdgcn_s_setprio(0);

#pragma unroll
    for (int i = 0; i < 16; ++i) sa[i] = exp2f(sa[i]);

    __builtin_amdgcn_s_setprio(1);
#pragma unroll
    for (int sp = 0; sp < 2; ++sp) {
      const int rb = 8 * sp;
      unsigned x0 = cvtpk_bf16(sa[rb + 0], sa[rb + 1]);
      unsigned x1 = cvtpk_bf16(sa[rb + 2], sa[rb + 3]);
      unsigned y0 = cvtpk_bf16(sa[rb + 4], sa[rb + 5]);
      unsigned y1 = cvtpk_bf16(sa[rb + 6], sa[rb + 7]);
      asm("v_permlane32_swap_b32 %0, %1" : "+v"(x0), "+v"(y0));
      asm("v_permlane32_swap_b32 %0, %1" : "+v"(x1), "+v"(y1));
      union { unsigned u[4]; s16x8 v; } pfv;
      pfv.u[0] = x0; pfv.u[1] = x1; pfv.u[2] = y0; pfv.u[3] = y1;
      s16x8 v0 = ldfrag(Vc, q, kg * 64 + 32 * sp + 16 * hi);
      s16x8 v1 = ldfrag(Vc, 32 + q, kg * 64 + 32 * sp + 16 * hi);
      oac0 = MFMA32(v0, pfv.v, oac0);
      oac1 = MFMA32(v1, pfv.v, oac1);
      lacc = MFMA32(onesv, pfv.v, lacc);
    }
    __builtin_amdgcn_s_setprio(0);
  };

  STAGE(0);
  WAITVM(0);
  RAWBAR();
  for (int i = 0; i < 15; ++i) {
    STAGE(16384);
    compute(0);
    WAITVM(0);
    RAWBAR();
    STAGE(0);
    compute(16384);
    WAITVM(0);
    RAWBAR();
  }
  STAGE(16384);
  compute(0);
  WAITVM(0);
  RAWBAR();
  compute(16384);
#undef STAGE

  __syncthreads();
  float* red = (float*)lds;
  if (kg == 1) {
    float* myr = red + (qg * 64 + lane) * 33;
#pragma unroll
    for (int i = 0; i < 16; ++i) { myr[i] = oac0[i]; myr[16 + i] = oac1[i]; }
    myr[32] = lacc[0];
  }
  __syncthreads();
  if (kg == 0) {
    const float* pr = red + (qg * 64 + lane) * 33;
#pragma unroll
    for (int i = 0; i < 16; ++i) { oac0[i] += pr[i]; oac1[i] += pr[16 + i]; }
    const float inv = 1.f / (lacc[0] + pr[32]);
    const size_t row = (size_t)(b * SS + q0 + qg * 32 + q);
    u16* orow = xb + row * DD + qcol;
#pragma unroll
    for (int rr = 0; rr < 4; ++rr) {
      uint2 pw0, pw1;
      pw0.x = cvtpk_bf16(oac0[4 * rr] * inv, oac0[4 * rr + 1] * inv);
      pw0.y = cvtpk_bf16(oac0[4 * rr + 2] * inv, oac0[4 * rr + 3] * inv);
      pw1.x = cvtpk_bf16(oac1[4 * rr] * inv, oac1[4 * rr + 1] * inv);
      pw1.y = cvtpk_bf16(oac1[4 * rr + 2] * inv, oac1[4 * rr + 3] * inv);
      *(uint2*)(orow + 8 * rr + 4 * hi) = pw0;
      *(uint2*)(orow + 32 + 8 * rr + 4 * hi) = pw1;
    }
  }
}

// ---------------------------------------------------------------------------
// prep_all: one kernel for all preprocessing (R10/R14-verified, ~26us win).
// ---------------------------------------------------------------------------
__global__ __launch_bounds__(256) void prep_all(
    const float* __restrict__ src, u16* __restrict__ srcb,
    const float* __restrict__ Wq, const float* __restrict__ Wk,
    const float* __restrict__ Wv, const float* __restrict__ Wo,
    u16* __restrict__ wqkvT, u16* __restrict__ woT,
    const float* __restrict__ W1, u16* __restrict__ w1T,
    const float* __restrict__ W2, u16* __restrict__ w2T,
    const float* __restrict__ bq, const float* __restrict__ bk,
    const float* __restrict__ bvv, float* __restrict__ bqkv) {
  const int id = blockIdx.x;
  const int t = threadIdx.x;
  __shared__ float T[32][33];

  if (id < 8192) {  // cvt
    int i = id * 256 + t;
    float4 v = ((const float4*)src)[i];
    u16x4 o;
    o[0] = f2bf(v.x); o[1] = f2bf(v.y); o[2] = f2bf(v.z); o[3] = f2bf(v.w);
    ((u16x4*)srcb)[i] = o;
    return;
  }
  const int id2 = id - 8192;
  if (id2 >= 12288) {  // concat
    int i = (id2 - 12288) * 256 + t;
    if (i < 3072)
      bqkv[i] = i < 1024 ? bq[i] : (i < 2048 ? bk[i - 1024] : bvv[i - 2048]);
    return;
  }
  const float* W; u16* Wt; int K, N, bx, by;
  if (id2 < 4096) {
    const int which = id2 >> 10, tile = id2 & 1023;
    W = (which == 0) ? Wq : (which == 1) ? Wk : (which == 2) ? Wv : Wo;
    Wt = (which == 3) ? woT : wqkvT + (size_t)which * 1024 * 1024;
    K = 1024; N = 1024; bx = tile & 31; by = tile >> 5;
  } else if (id2 < 8192) {
    const int tile = id2 - 4096;
    W = W1; Wt = w1T; K = 1024; N = 4096; bx = tile & 127; by = tile >> 7;
  } else {
    const int tile = id2 - 8192;
    W = W2; Wt = w2T; K = 4096; N = 1024; bx = tile & 31; by = tile >> 5;
  }
  const int n0 = bx * 32, k0 = by * 32;
  const int r = t >> 3, c = (t & 7) * 4;
  float4 v = *(const float4*)&W[(size_t)(k0 + r) * N + n0 + c];
  T[r][c] = v.x; T[r][c + 1] = v.y; T[r][c + 2] = v.z; T[r][c + 3] = v.w;
  __syncthreads();
  const int a = t >> 3, b0 = (t & 7) * 4;
  u16x4 o;
#pragma unroll
  for (int jj = 0; jj < 4; ++jj) o[jj] = f2bf(T[b0 + jj][a]);
  *(u16x4*)&Wt[(size_t)(n0 + a) * K + k0 + b0] = o;
}

// ---------------------------------------------------------------------------
// Residual + LayerNorm. XBF: X supplied as bf16. WB: write bf16. WF: write f32.
// ---------------------------------------------------------------------------
template <int WB, int WF, int XBF>
__global__ __launch_bounds__(256) void ln_res(
    const float* __restrict__ Xf, const u16* __restrict__ Xb,
    const float* __restrict__ R, const float* __restrict__ g,
    const float* __restrict__ b, float* __restrict__ Y,
    u16* __restrict__ Yb) {
  const int row = blockIdx.x;
  const int t = threadIdx.x;
  const size_t off = (size_t)row * DD + t * 4;

  float v0, v1, v2, v3;
  if (XBF) {
    u16x4 x4 = *(const u16x4*)&Xb[off];
    v0 = bf2f(x4[0]); v1 = bf2f(x4[1]); v2 = bf2f(x4[2]); v3 = bf2f(x4[3]);
  } else {
    float4 x4 = *(const float4*)&Xf[off];
    v0 = x4.x; v1 = x4.y; v2 = x4.z; v3 = x4.w;
  }
  float4 r4 = *(const float4*)&R[off];
  v0 += r4.x; v1 += r4.y; v2 += r4.z; v3 += r4.w;

  float s1 = v0 + v1 + v2 + v3;
  float s2 = v0 * v0 + v1 * v1 + v2 * v2 + v3 * v3;
#pragma unroll
  for (int o = 1; o < 64; o <<= 1) {
    s1 += __shfl_xor(s1, o);
    s2 += __shfl_xor(s2, o);
  }
  __shared__ float red1[4], red2[4];
  if ((t & 63) == 0) {
    red1[t >> 6] = s1;
    red2[t >> 6] = s2;
  }
  __syncthreads();
  s1 = red1[0] + red1[1] + red1[2] + red1[3];
  s2 = red2[0] + red2[1] + red2[2] + red2[3];

  const float mu = s1 * (1.f / DD);
  const float var = s2 * (1.f / DD) - mu * mu;
  const float rs = rsqrtf(var + 1e-5f);

  float4 g4 = *(const float4*)&g[t * 4];
  float4 b4 = *(const float4*)&b[t * 4];
  float4 y;
  y.x = (v0 - mu) * rs * g4.x + b4.x;
  y.y = (v1 - mu) * rs * g4.y + b4.y;
  y.z = (v2 - mu) * rs * g4.z + b4.z;
  y.w = (v3 - mu) * rs * g4.w + b4.w;
  if (WF) *(float4*)&Y[off] = y;
  if (WB) {
    u16x4 o;
    o[0] = f2bf(y.x); o[1] = f2bf(y.y); o[2] = f2bf(y.z); o[3] = f2bf(y.w);
    *(u16x4*)&Yb[off] = o;
  }
}

// ---------------------------------------------------------------------------
extern "C" void kernel_launch(void* const* d_in, const int* in_sizes, int n_in,
                              void* d_out, int out_size, void* d_ws,
                              size_t ws_size, hipStream_t stream) {
  const float* src = (const float*)d_in[0];
  const float* Wq  = (const float*)d_in[1];
  const float* bq  = (const float*)d_in[2];
  const float* Wk  = (const float*)d_in[3];
  const float* bk  = (const float*)d_in[4];
  const float* Wv  = (const float*)d_in[5];
  const float* bv  = (const float*)d_in[6];
  const float* Wo  = (const float*)d_in[7];
  const float* bo  = (const float*)d_in[8];
  const float* g1  = (const float*)d_in[9];
  const float* b1  = (const float*)d_in[10];
  const float* W1  = (const float*)d_in[11];
  const float* bf1 = (const float*)d_in[12];
  const float* W2  = (const float*)d_in[13];
  const float* bf2 = (const float*)d_in[14];
  const float* g2  = (const float*)d_in[15];
  const float* b2  = (const float*)d_in[16];

  char* W = (char*)d_ws;
  u16*   wqkvT = (u16*)  (W + 0);          //  6,291,456
  u16*   woT   = (u16*)  (W + 6291456);    //  2,097,152
  u16*   w1T   = (u16*)  (W + 8388608);    //  8,388,608
  u16*   w2T   = (u16*)  (W + 16777216);   //  8,388,608
  float* bqkv  = (float*)(W + 25165824);   //     12,288
  u16*   srcb  = (u16*)  (W + 25178112);   // 16,777,216
  u16*   qkv   = (u16*)  (W + 41955328);   // 50,331,648 (V cols unused)
  u16*   vt    = (u16*)  (W + 92286976);   // 16,777,216
  u16*   xb    = (u16*)  (W + 109064192);  // 16,777,216
  float* pb    = (float*)(W + 125841408);  // 33,554,432
  u16*   s1bb  = (u16*)  (W + 109064192);  // alias xb (dead after Wo GEMM)
  u16*   f1b   = (u16*)  (W + 41955328);   // alias qkv+vt (dead after attn)
  float* f2b   = (float*)(W + 125841408);  // alias pb (dead after LN1)

  dim3 blk(256);

  // all prep in one launch (cvt + 6 transposes + concat)
  prep_all<<<20492, blk, 0, stream>>>(src, srcb, Wq, Wk, Wv, Wo, wqkvT, woT,
                                      W1, w1T, W2, w2T, bq, bk, bv, bqkv);

  // fused QKV projection: Q (pre-scaled) + K -> qkv; V -> vt (transposed)
  gemm256<0, 1, 1, 1><<<384, 512, 0, stream>>>(
      srcb, wqkvT, bqkv, nullptr, qkv, vt, MR, 3072, DD, 12);
  // attention v8 (4 blocks/CU, 64 VGPR)
  attn_mfma<<<2048, blk, 0, stream>>>(qkv, vt, xb);
  // output projection (128x128)
  gemm128<0><<<512, blk, 0, stream>>>(xb, woT, bo, pb, MR, DD, DD, 8);
  // residual + LN1 -> bf16 only
  ln_res<1, 0, 0><<<MR, blk, 0, stream>>>(src, nullptr, pb, g1, b1, nullptr,
                                          s1bb);
  // FFN1 (ReLU, bf16 out)
  gemm256<1, 1, 0, 0><<<512, 512, 0, stream>>>(
      s1bb, w1T, bf1, nullptr, f1b, nullptr, MR, PFF, DD, 16);
  // FFN2 (f32 out, 128x128)
  gemm128<0><<<512, blk, 0, stream>>>(f1b, w2T, bf2, f2b, MR, DD, PFF, 8);
  // residual (bf16 s1) + LN2 -> output f32
  ln_res<0, 1, 1><<<MR, blk, 0, stream>>>(nullptr, s1bb, f2b, g2, b2,
                                          (float*)d_out, nullptr);
}